// Round 7
// baseline (209.889 us; speedup 1.0000x reference)
//
#include <hip/hip_runtime.h>

// Problem constants (B=2, C=64, H=W=192, EXP=4, DG=4, K=3)
#define BN   2
#define CN   64
#define HN   192
#define WN   192
#define HWN  36864          // 192*192
#define OCN  256            // EXP*C
#define JCN  72             // DG*2*9
#define SN   32             // pixel strip for deform

// k_deform tile geometry (window covers |offset| < ~3-4; fallback guards rest)
#define DROWS 8             // output rows per block
#define XH    17            // staged x rows
#define XW    42            // staged x cols
#define XRT   4             // row halo top
#define XCL   4             // col halo left

// k_offsets MFMA geometry
#define PITCH 264           // bf16 pitch of xd row (256 + 8 pad)

typedef __attribute__((ext_vector_type(8))) short bf16x8;
typedef __attribute__((ext_vector_type(4))) float f32x4;

__device__ __forceinline__ unsigned short f2bf(float f) {
    union { float f; unsigned u; } v; v.f = f;
    unsigned r = v.u + 0x7fffu + ((v.u >> 16) & 1u);
    return (unsigned short)(r >> 16);
}

// ---------------------------------------------------------------------------
// Prep:
//  job 1: w2mf = w2 (72x256) in bf16, swizzled to MFMA A-fragment order.
//  job 2: w_outT[c*64+o] = w_out[o*64+c]
// ---------------------------------------------------------------------------
__global__ __launch_bounds__(256) void k_prep(const float* __restrict__ w2,
                                              const float* __restrict__ w_out,
                                              unsigned short* __restrict__ w2mf,
                                              float* __restrict__ w_outT) {
    int idx = blockIdx.x * 256 + threadIdx.x;
    if (idx < 20480) {
        int j  = idx & 7;
        int l  = (idx >> 3) & 63;
        int ts = idx >> 9;             // tm*8+s, 0..39
        int tm = ts >> 3, s = ts & 7;
        int jrow = tm * 16 + (l & 15);
        int k    = s * 32 + (l >> 4) * 8 + j;
        float v = (jrow < JCN) ? w2[jrow * OCN + k] : 0.f;
        w2mf[idx] = f2bf(v);
    } else if (idx < 24576) {
        int r = idx - 20480;
        int c = r >> 6, o = r & 63;
        w_outT[r] = w_out[o * CN + c];
    }
}

// ---------------------------------------------------------------------------
// K1: offsets t + fused x1 copy.  MFMA version (unchanged).
// ---------------------------------------------------------------------------
__global__ __launch_bounds__(256, 4) void k_offsets(const float* __restrict__ x,
                                                    const float* __restrict__ w1,
                                                    const unsigned short* __restrict__ w2mf,
                                                    const float* __restrict__ b2,
                                                    float* __restrict__ t_out,
                                                    float* __restrict__ x_copy) {
    __shared__ unsigned short xd[64 * PITCH];       // 33792 B
    const int x0  = blockIdx.x * 64;
    const int y   = blockIdx.y;
    const int b   = blockIdx.z;
    const int tid = threadIdx.x;
    const int px  = tid & 63;
    const int wv  = tid >> 6;                       // wave id 0..3
    const int xcol = x0 + px;
    const float* xb = x + (size_t)b * CN * HWN;

    auto load_round = [&](int r, float (*ld)[9]) {
        #pragma unroll
        for (int cc = 0; cc < 4; ++cc) {
            int c = r * 16 + cc * 4 + wv;
            const float* xp = xb + (size_t)c * HWN;
            #pragma unroll
            for (int k = 0; k < 9; ++k) {
                int ky = k / 3, kx = k - 3 * ky;
                int yy = y - 1 + ky, xx = xcol - 1 + kx;
                float v = 0.f;
                if ((unsigned)yy < (unsigned)HN && (unsigned)xx < (unsigned)WN)
                    v = xp[yy * WN + xx];
                ld[cc][k] = v;
            }
        }
    };
    auto conv_round = [&](int r, float (*ld)[9]) {
        #pragma unroll
        for (int cc = 0; cc < 4; ++cc) {
            int c = r * 16 + cc * 4 + wv;
            float ctr = ld[cc][4];
            x_copy[((size_t)b * CN + c) * HWN + y * WN + xcol] = ctr;
            const float* wr = w1 + (size_t)(c * 4) * 9;
            float d[9];
            #pragma unroll
            for (int k = 0; k < 9; ++k) d[k] = ld[cc][k] - ctr;
            unsigned short bq[4];
            #pragma unroll
            for (int e = 0; e < 4; ++e) {
                float a = 0.f;
                #pragma unroll
                for (int k = 0; k < 9; ++k)
                    if (k != 4) a += wr[e * 9 + k] * d[k];
                bq[e] = f2bf(a);
            }
            uint2 uu;
            uu.x = (unsigned)bq[0] | ((unsigned)bq[1] << 16);
            uu.y = (unsigned)bq[2] | ((unsigned)bq[3] << 16);
            *(uint2*)(&xd[px * PITCH + c * 4]) = uu;   // o = 4c..4c+3
        }
    };

    float lbuf[2][4][9];
    load_round(0, lbuf[0]);
    #pragma unroll
    for (int r = 0; r < 4; ++r) {
        if (r < 3) load_round(r + 1, lbuf[(r + 1) & 1]);
        conv_round(r, lbuf[r & 1]);
    }
    __syncthreads();

    // Phase B
    const int lane = tid & 63;
    const int q    = lane >> 4;
    const int c15  = lane & 15;
    const int n0   = wv * 16;

    bf16x8 bfr[8];
    {
        const unsigned short* bp = xd + (size_t)(n0 + c15) * PITCH + q * 8;
        #pragma unroll
        for (int s = 0; s < 8; ++s)
            bfr[s] = *(const bf16x8*)(bp + s * 32);
    }

    f32x4 acc[5];
    #pragma unroll
    for (int t = 0; t < 5; ++t) acc[t] = (f32x4){0.f, 0.f, 0.f, 0.f};

    const bf16x8* ap = (const bf16x8*)w2mf + lane;
    #pragma unroll
    for (int tm = 0; tm < 5; ++tm) {
        #pragma unroll
        for (int s = 0; s < 8; ++s) {
            bf16x8 af = ap[(tm * 8 + s) * 64];
            acc[tm] = __builtin_amdgcn_mfma_f32_16x16x32_bf16(af, bfr[s], acc[tm], 0, 0, 0);
        }
    }

    float* tb = t_out + (size_t)b * JCN * HWN + y * WN + x0 + n0 + c15;
    #pragma unroll
    for (int tm = 0; tm < 5; ++tm) {
        #pragma unroll
        for (int r = 0; r < 4; ++r) {
            int j = tm * 16 + q * 4 + r;
            if (j < JCN)
                tb[(size_t)j * HWN] = acc[tm][r] + b2[j];
        }
    }
}

// ---------------------------------------------------------------------------
// K2: depthwise deformable conv.
// Thread = (row r, px); offsets prefetched to REGISTERS (no ts LDS);
// x window in LDS (23 KB -> 5+ blocks/CU); channels inner loop.
// ---------------------------------------------------------------------------
__device__ __forceinline__ float dsample(const float* __restrict__ p, int yi, int xi) {
    if ((unsigned)yi < (unsigned)HN && (unsigned)xi < (unsigned)WN)
        return p[yi * WN + xi];
    return 0.f;
}

__global__ __launch_bounds__(256, 5) void k_deform(const float* __restrict__ x,
                                                   const float* __restrict__ t_in,
                                                   const float* __restrict__ wdef,
                                                   float* __restrict__ y_out) {
    __shared__ float xs[8 * XH * XW];                 // 22848 B
    __shared__ float wks[9 * 8];                      // [k][cc]
    __shared__ float wsums[8];
    const int x0   = blockIdx.x * SN;
    const int yr0  = blockIdx.y * DROWS;
    const int zz   = blockIdx.z;
    const int b    = zz >> 3;
    const int chunk = zz & 7;                         // 8-channel chunk
    const int g    = chunk >> 1;                      // deform group
    const int tid  = threadIdx.x;
    const int r    = tid >> 5;                        // output row within tile
    const int px   = tid & 31;
    const int row_lo = yr0 - XRT;
    const int col_lo = x0 - XCL;
    const float* xb = x + (size_t)b * CN * HWN;

    // prefetch this thread's 18 offsets into registers (coalesced)
    float dyr[9], dxr[9];
    {
        const float* tbp = t_in + ((size_t)b * JCN + g * 18) * HWN
                         + (yr0 + r) * WN + x0 + px;
        #pragma unroll
        for (int k = 0; k < 9; ++k) {
            dyr[k] = tbp[(size_t)(2 * k) * HWN];
            dxr[k] = tbp[(size_t)(2 * k + 1) * HWN];
        }
    }

    // stage x window (zero-filled outside image)
    for (int idx = tid; idx < 8 * XH * XW; idx += 256) {
        int cc  = idx / (XH * XW);
        int rem = idx - cc * (XH * XW);
        int rr  = rem / XW;
        int col = rem - rr * XW;
        int yy  = row_lo + rr;
        int xx  = col_lo + col;
        float v = 0.f;
        if ((unsigned)yy < (unsigned)HN && (unsigned)xx < (unsigned)WN)
            v = xb[(size_t)(chunk * 8 + cc) * HWN + yy * WN + xx];
        xs[idx] = v;
    }
    // stage weights
    if (tid < 72) {
        int k = tid >> 3, cc = tid & 7;
        wks[tid] = wdef[(chunk * 8 + cc) * 9 + k];
    } else if (tid < 80) {
        int cc = tid - 72;
        float s = 0.f;
        #pragma unroll
        for (int k = 0; k < 9; ++k) s += wdef[(chunk * 8 + cc) * 9 + k];
        wsums[cc] = s;
    }
    __syncthreads();

    float acc[8];
    #pragma unroll
    for (int c = 0; c < 8; ++c)
        acc[c] = -xs[c * (XH * XW) + (XRT + r) * XW + XCL + px] * wsums[c];

    const float ry_basef = (float)(yr0 + r - 1);
    const float rx_basef = (float)(x0 + px - 1);

    #pragma unroll
    for (int k = 0; k < 9; ++k) {
        const int ky = k / 3, kx = k - 3 * ky;
        float py  = ry_basef + (float)ky + dyr[k];
        float pxf = rx_basef + (float)kx + dxr[k];
        float y0f = floorf(py), x0f = floorf(pxf);
        float wy = py - y0f, wx = pxf - x0f;
        int yi = (int)y0f, xi = (int)x0f;
        int ry = yi - row_lo, rx = xi - col_lo;
        float omwy = 1.f - wy, omwx = 1.f - wx;
        float w00 = omwy * omwx;
        float w01 = omwy * wx;
        float w10 = wy * omwx;
        float w11 = wy * wx;
        float4 wka = *(const float4*)&wks[k * 8];
        float4 wkb = *(const float4*)&wks[k * 8 + 4];
        float wkv[8] = {wka.x, wka.y, wka.z, wka.w, wkb.x, wkb.y, wkb.z, wkb.w};
        if ((unsigned)ry < (XH - 1) && (unsigned)rx < (XW - 1)) {
            const float* p0 = xs + ry * XW + rx;
            #pragma unroll
            for (int c = 0; c < 8; ++c) {
                const float* p = p0 + c * (XH * XW);
                float bil = p[0] * w00 + p[1] * w01 + p[XW] * w10 + p[XW + 1] * w11;
                acc[c] += wkv[c] * bil;
            }
        } else {
            #pragma unroll
            for (int c = 0; c < 8; ++c) {
                const float* xp = xb + (size_t)(chunk * 8 + c) * HWN;
                float v00 = dsample(xp, yi,     xi);
                float v01 = dsample(xp, yi,     xi + 1);
                float v10 = dsample(xp, yi + 1, xi);
                float v11 = dsample(xp, yi + 1, xi + 1);
                float bil = v00 * w00 + v01 * w01 + v10 * w10 + v11 * w11;
                acc[c] += wkv[c] * bil;
            }
        }
    }

    float* yo = y_out + ((size_t)b * CN + chunk * 8) * HWN + (yr0 + r) * WN + x0 + px;
    #pragma unroll
    for (int c = 0; c < 8; ++c)
        yo[(size_t)c * HWN] = acc[c];
}

// ---------------------------------------------------------------------------
// K3: m = w_out . y  (64-px tile, pre-transposed weights, 16 o/thread)
// ---------------------------------------------------------------------------
__global__ __launch_bounds__(256, 4) void k_final(const float* __restrict__ y_in,
                                                  const float* __restrict__ w_outT,
                                                  float* __restrict__ m_out) {
    __shared__ float lds_y[CN * 64];     // 16 KB
    __shared__ float ldsw[CN * CN];      // 16 KB  [c][o]
    const int x0  = blockIdx.x * 64;
    const int yr  = blockIdx.y;
    const int b   = blockIdx.z;
    const int tid = threadIdx.x;

    for (int idx = tid; idx < CN * CN; idx += 256) ldsw[idx] = w_outT[idx];
    for (int idx = tid; idx < CN * 64; idx += 256) {
        int c  = idx >> 6;
        int px = idx & 63;
        lds_y[idx] = y_in[((size_t)b * CN + c) * HWN + yr * WN + x0 + px];
    }
    __syncthreads();

    const int px = tid & 63;
    const int og = tid >> 6;                      // 16 o's per thread
    float acc[16];
    #pragma unroll
    for (int i = 0; i < 16; ++i) acc[i] = 0.f;
    #pragma unroll 4
    for (int c = 0; c < CN; ++c) {
        float yv = lds_y[c * 64 + px];
        const float4* wr = (const float4*)(ldsw + c * CN + og * 16);
        float4 w0 = wr[0], w1 = wr[1], w2 = wr[2], w3 = wr[3];
        acc[0]  += w0.x * yv; acc[1]  += w0.y * yv; acc[2]  += w0.z * yv; acc[3]  += w0.w * yv;
        acc[4]  += w1.x * yv; acc[5]  += w1.y * yv; acc[6]  += w1.z * yv; acc[7]  += w1.w * yv;
        acc[8]  += w2.x * yv; acc[9]  += w2.y * yv; acc[10] += w2.z * yv; acc[11] += w2.w * yv;
        acc[12] += w3.x * yv; acc[13] += w3.y * yv; acc[14] += w3.z * yv; acc[15] += w3.w * yv;
    }
    #pragma unroll
    for (int i = 0; i < 16; ++i) {
        int o = og * 16 + i;
        m_out[((size_t)b * CN + o) * HWN + yr * WN + x0 + px] = acc[i];
    }
}

// ---------------------------------------------------------------------------
extern "C" void kernel_launch(void* const* d_in, const int* in_sizes, int n_in,
                              void* d_out, int out_size, void* d_ws, size_t ws_size,
                              hipStream_t stream) {
    const float* x1    = (const float*)d_in[0];   // 2*64*192*192
    const float* w_off1 = (const float*)d_in[1];  // 256*9
    const float* w_off2 = (const float*)d_in[2];  // 72*256
    const float* b_off2 = (const float*)d_in[3];  // 72
    const float* w_def = (const float*)d_in[4];   // 64*9
    const float* w_out = (const float*)d_in[5];   // 64*64

    float* out = (float*)d_out;
    const size_t n_x = (size_t)BN * CN * HWN;     // 4718592
    float* out_x1 = out;                          // output 0: x1 copy (fused into k_offsets)
    float* out_m  = out + n_x;                    // output 1: m

    // Workspace layout (bytes)
    char* ws0 = (char*)d_ws;
    unsigned short* w2mf = (unsigned short*)ws0;            // 20480 bf16 = 40960 B
    float* w_outT = (float*)(ws0 + 40960);                  // 4096 f = 16384 B
    float* t_ws   = (float*)(ws0 + 57344);                  // 2*72*36864 f
    float* y_ws   = t_ws + (size_t)BN * JCN * HWN;          // 2*64*36864 f

    dim3 blk(256);

    k_prep<<<dim3(96), blk, 0, stream>>>(w_off2, w_out, w2mf, w_outT);
    k_offsets<<<dim3(WN / 64, HN, BN), blk, 0, stream>>>(x1, w_off1, w2mf, b_off2,
                                                         t_ws, out_x1);
    k_deform<<<dim3(WN / SN, HN / DROWS, BN * 8), blk, 0, stream>>>(x1, t_ws, w_def, y_ws);
    k_final<<<dim3(WN / 64, HN, BN), blk, 0, stream>>>(y_ws, w_outT, out_m);
}

// Round 8
// 202.126 us; speedup vs baseline: 1.0384x; 1.0384x over previous
//
#include <hip/hip_runtime.h>

// Problem constants (B=2, C=64, H=W=192, EXP=4, DG=4, K=3)
#define BN   2
#define CN   64
#define HN   192
#define WN   192
#define HWN  36864          // 192*192
#define OCN  256            // EXP*C
#define JCN  72             // DG*2*9
#define SN   32             // pixel strip for deform

// k_deform tile geometry (window covers |offset| < ~3-4; fallback guards rest)
#define DROWS 8             // output rows per block
#define XH    17            // staged x rows
#define XW    42            // staged x cols
#define XRT   4             // row halo top
#define XCL   4             // col halo left

// k_offsets MFMA geometry
#define PITCH 264           // bf16 pitch of xd row (256 + 8 pad)

typedef __attribute__((ext_vector_type(8))) short bf16x8;
typedef __attribute__((ext_vector_type(4))) float f32x4;

__device__ __forceinline__ unsigned short f2bf(float f) {
    union { float f; unsigned u; } v; v.f = f;
    unsigned r = v.u + 0x7fffu + ((v.u >> 16) & 1u);
    return (unsigned short)(r >> 16);
}

// ---------------------------------------------------------------------------
// Prep:
//  job 1: w2mf = w2 (72x256) in bf16, swizzled to MFMA A-fragment order.
//  job 2: w_outT[c*64+o] = w_out[o*64+c]
// ---------------------------------------------------------------------------
__global__ __launch_bounds__(256) void k_prep(const float* __restrict__ w2,
                                              const float* __restrict__ w_out,
                                              unsigned short* __restrict__ w2mf,
                                              float* __restrict__ w_outT) {
    int idx = blockIdx.x * 256 + threadIdx.x;
    if (idx < 20480) {
        int j  = idx & 7;
        int l  = (idx >> 3) & 63;
        int ts = idx >> 9;             // tm*8+s, 0..39
        int tm = ts >> 3, s = ts & 7;
        int jrow = tm * 16 + (l & 15);
        int k    = s * 32 + (l >> 4) * 8 + j;
        float v = (jrow < JCN) ? w2[jrow * OCN + k] : 0.f;
        w2mf[idx] = f2bf(v);
    } else if (idx < 24576) {
        int r = idx - 20480;
        int c = r >> 6, o = r & 63;
        w_outT[r] = w_out[o * CN + c];
    }
}

// ---------------------------------------------------------------------------
// K1: offsets t + fused x1 copy.  MFMA version (unchanged).
// ---------------------------------------------------------------------------
__global__ __launch_bounds__(256, 4) void k_offsets(const float* __restrict__ x,
                                                    const float* __restrict__ w1,
                                                    const unsigned short* __restrict__ w2mf,
                                                    const float* __restrict__ b2,
                                                    float* __restrict__ t_out,
                                                    float* __restrict__ x_copy) {
    __shared__ unsigned short xd[64 * PITCH];       // 33792 B
    const int x0  = blockIdx.x * 64;
    const int y   = blockIdx.y;
    const int b   = blockIdx.z;
    const int tid = threadIdx.x;
    const int px  = tid & 63;
    const int wv  = tid >> 6;                       // wave id 0..3
    const int xcol = x0 + px;
    const float* xb = x + (size_t)b * CN * HWN;

    auto load_round = [&](int r, float (*ld)[9]) {
        #pragma unroll
        for (int cc = 0; cc < 4; ++cc) {
            int c = r * 16 + cc * 4 + wv;
            const float* xp = xb + (size_t)c * HWN;
            #pragma unroll
            for (int k = 0; k < 9; ++k) {
                int ky = k / 3, kx = k - 3 * ky;
                int yy = y - 1 + ky, xx = xcol - 1 + kx;
                float v = 0.f;
                if ((unsigned)yy < (unsigned)HN && (unsigned)xx < (unsigned)WN)
                    v = xp[yy * WN + xx];
                ld[cc][k] = v;
            }
        }
    };
    auto conv_round = [&](int r, float (*ld)[9]) {
        #pragma unroll
        for (int cc = 0; cc < 4; ++cc) {
            int c = r * 16 + cc * 4 + wv;
            float ctr = ld[cc][4];
            x_copy[((size_t)b * CN + c) * HWN + y * WN + xcol] = ctr;
            const float* wr = w1 + (size_t)(c * 4) * 9;
            float d[9];
            #pragma unroll
            for (int k = 0; k < 9; ++k) d[k] = ld[cc][k] - ctr;
            unsigned short bq[4];
            #pragma unroll
            for (int e = 0; e < 4; ++e) {
                float a = 0.f;
                #pragma unroll
                for (int k = 0; k < 9; ++k)
                    if (k != 4) a += wr[e * 9 + k] * d[k];
                bq[e] = f2bf(a);
            }
            uint2 uu;
            uu.x = (unsigned)bq[0] | ((unsigned)bq[1] << 16);
            uu.y = (unsigned)bq[2] | ((unsigned)bq[3] << 16);
            *(uint2*)(&xd[px * PITCH + c * 4]) = uu;   // o = 4c..4c+3
        }
    };

    float lbuf[2][4][9];
    load_round(0, lbuf[0]);
    #pragma unroll
    for (int r = 0; r < 4; ++r) {
        if (r < 3) load_round(r + 1, lbuf[(r + 1) & 1]);
        conv_round(r, lbuf[r & 1]);
    }
    __syncthreads();

    // Phase B
    const int lane = tid & 63;
    const int q    = lane >> 4;
    const int c15  = lane & 15;
    const int n0   = wv * 16;

    bf16x8 bfr[8];
    {
        const unsigned short* bp = xd + (size_t)(n0 + c15) * PITCH + q * 8;
        #pragma unroll
        for (int s = 0; s < 8; ++s)
            bfr[s] = *(const bf16x8*)(bp + s * 32);
    }

    f32x4 acc[5];
    #pragma unroll
    for (int t = 0; t < 5; ++t) acc[t] = (f32x4){0.f, 0.f, 0.f, 0.f};

    const bf16x8* ap = (const bf16x8*)w2mf + lane;
    #pragma unroll
    for (int tm = 0; tm < 5; ++tm) {
        #pragma unroll
        for (int s = 0; s < 8; ++s) {
            bf16x8 af = ap[(tm * 8 + s) * 64];
            acc[tm] = __builtin_amdgcn_mfma_f32_16x16x32_bf16(af, bfr[s], acc[tm], 0, 0, 0);
        }
    }

    float* tb = t_out + (size_t)b * JCN * HWN + y * WN + x0 + n0 + c15;
    #pragma unroll
    for (int tm = 0; tm < 5; ++tm) {
        #pragma unroll
        for (int r = 0; r < 4; ++r) {
            int j = tm * 16 + q * 4 + r;
            if (j < JCN)
                tb[(size_t)j * HWN] = acc[tm][r] + b2[j];
        }
    }
}

// ---------------------------------------------------------------------------
// K2: depthwise deformable conv.
// Thread = (row r, px); offsets prefetched to REGISTERS (no ts LDS);
// x window in LDS; channels inner loop.
// __launch_bounds__(256,4): VGPR budget ~128 — round 7's (256,5) forced
// VGPR=48 and spilled the offset registers to scratch (+83 MB WRITE_SIZE).
// ---------------------------------------------------------------------------
__device__ __forceinline__ float dsample(const float* __restrict__ p, int yi, int xi) {
    if ((unsigned)yi < (unsigned)HN && (unsigned)xi < (unsigned)WN)
        return p[yi * WN + xi];
    return 0.f;
}

__global__ __launch_bounds__(256, 4) void k_deform(const float* __restrict__ x,
                                                   const float* __restrict__ t_in,
                                                   const float* __restrict__ wdef,
                                                   float* __restrict__ y_out) {
    __shared__ float xs[8 * XH * XW];                 // 22848 B
    __shared__ float wks[9 * 8];                      // [k][cc]
    __shared__ float wsums[8];
    const int x0   = blockIdx.x * SN;
    const int yr0  = blockIdx.y * DROWS;
    const int zz   = blockIdx.z;
    const int b    = zz >> 3;
    const int chunk = zz & 7;                         // 8-channel chunk
    const int g    = chunk >> 1;                      // deform group
    const int tid  = threadIdx.x;
    const int r    = tid >> 5;                        // output row within tile
    const int px   = tid & 31;
    const int row_lo = yr0 - XRT;
    const int col_lo = x0 - XCL;
    const float* xb = x + (size_t)b * CN * HWN;

    // prefetch this thread's 18 offsets into registers (coalesced)
    float dyr[9], dxr[9];
    {
        const float* tbp = t_in + ((size_t)b * JCN + g * 18) * HWN
                         + (yr0 + r) * WN + x0 + px;
        #pragma unroll
        for (int k = 0; k < 9; ++k) {
            dyr[k] = tbp[(size_t)(2 * k) * HWN];
            dxr[k] = tbp[(size_t)(2 * k + 1) * HWN];
        }
    }

    // stage x window (zero-filled outside image)
    for (int idx = tid; idx < 8 * XH * XW; idx += 256) {
        int cc  = idx / (XH * XW);
        int rem = idx - cc * (XH * XW);
        int rr  = rem / XW;
        int col = rem - rr * XW;
        int yy  = row_lo + rr;
        int xx  = col_lo + col;
        float v = 0.f;
        if ((unsigned)yy < (unsigned)HN && (unsigned)xx < (unsigned)WN)
            v = xb[(size_t)(chunk * 8 + cc) * HWN + yy * WN + xx];
        xs[idx] = v;
    }
    // stage weights
    if (tid < 72) {
        int k = tid >> 3, cc = tid & 7;
        wks[tid] = wdef[(chunk * 8 + cc) * 9 + k];
    } else if (tid < 80) {
        int cc = tid - 72;
        float s = 0.f;
        #pragma unroll
        for (int k = 0; k < 9; ++k) s += wdef[(chunk * 8 + cc) * 9 + k];
        wsums[cc] = s;
    }
    __syncthreads();

    float acc[8];
    #pragma unroll
    for (int c = 0; c < 8; ++c)
        acc[c] = -xs[c * (XH * XW) + (XRT + r) * XW + XCL + px] * wsums[c];

    const float ry_basef = (float)(yr0 + r - 1);
    const float rx_basef = (float)(x0 + px - 1);

    #pragma unroll
    for (int k = 0; k < 9; ++k) {
        const int ky = k / 3, kx = k - 3 * ky;
        float py  = ry_basef + (float)ky + dyr[k];
        float pxf = rx_basef + (float)kx + dxr[k];
        float y0f = floorf(py), x0f = floorf(pxf);
        float wy = py - y0f, wx = pxf - x0f;
        int yi = (int)y0f, xi = (int)x0f;
        int ry = yi - row_lo, rx = xi - col_lo;
        float omwy = 1.f - wy, omwx = 1.f - wx;
        float w00 = omwy * omwx;
        float w01 = omwy * wx;
        float w10 = wy * omwx;
        float w11 = wy * wx;
        float4 wka = *(const float4*)&wks[k * 8];
        float4 wkb = *(const float4*)&wks[k * 8 + 4];
        float wkv[8] = {wka.x, wka.y, wka.z, wka.w, wkb.x, wkb.y, wkb.z, wkb.w};
        if ((unsigned)ry < (XH - 1) && (unsigned)rx < (XW - 1)) {
            const float* p0 = xs + ry * XW + rx;
            #pragma unroll
            for (int c = 0; c < 8; ++c) {
                const float* p = p0 + c * (XH * XW);
                float bil = p[0] * w00 + p[1] * w01 + p[XW] * w10 + p[XW + 1] * w11;
                acc[c] += wkv[c] * bil;
            }
        } else {
            #pragma unroll
            for (int c = 0; c < 8; ++c) {
                const float* xp = xb + (size_t)(chunk * 8 + c) * HWN;
                float v00 = dsample(xp, yi,     xi);
                float v01 = dsample(xp, yi,     xi + 1);
                float v10 = dsample(xp, yi + 1, xi);
                float v11 = dsample(xp, yi + 1, xi + 1);
                float bil = v00 * w00 + v01 * w01 + v10 * w10 + v11 * w11;
                acc[c] += wkv[c] * bil;
            }
        }
    }

    float* yo = y_out + ((size_t)b * CN + chunk * 8) * HWN + (yr0 + r) * WN + x0 + px;
    #pragma unroll
    for (int c = 0; c < 8; ++c)
        yo[(size_t)c * HWN] = acc[c];
}

// ---------------------------------------------------------------------------
// K3: m = w_out . y  (64-px tile, pre-transposed weights, 16 o/thread)
// ---------------------------------------------------------------------------
__global__ __launch_bounds__(256, 4) void k_final(const float* __restrict__ y_in,
                                                  const float* __restrict__ w_outT,
                                                  float* __restrict__ m_out) {
    __shared__ float lds_y[CN * 64];     // 16 KB
    __shared__ float ldsw[CN * CN];      // 16 KB  [c][o]
    const int x0  = blockIdx.x * 64;
    const int yr  = blockIdx.y;
    const int b   = blockIdx.z;
    const int tid = threadIdx.x;

    for (int idx = tid; idx < CN * CN; idx += 256) ldsw[idx] = w_outT[idx];
    for (int idx = tid; idx < CN * 64; idx += 256) {
        int c  = idx >> 6;
        int px = idx & 63;
        lds_y[idx] = y_in[((size_t)b * CN + c) * HWN + yr * WN + x0 + px];
    }
    __syncthreads();

    const int px = tid & 63;
    const int og = tid >> 6;                      // 16 o's per thread
    float acc[16];
    #pragma unroll
    for (int i = 0; i < 16; ++i) acc[i] = 0.f;
    #pragma unroll 4
    for (int c = 0; c < CN; ++c) {
        float yv = lds_y[c * 64 + px];
        const float4* wr = (const float4*)(ldsw + c * CN + og * 16);
        float4 w0 = wr[0], w1 = wr[1], w2 = wr[2], w3 = wr[3];
        acc[0]  += w0.x * yv; acc[1]  += w0.y * yv; acc[2]  += w0.z * yv; acc[3]  += w0.w * yv;
        acc[4]  += w1.x * yv; acc[5]  += w1.y * yv; acc[6]  += w1.z * yv; acc[7]  += w1.w * yv;
        acc[8]  += w2.x * yv; acc[9]  += w2.y * yv; acc[10] += w2.z * yv; acc[11] += w2.w * yv;
        acc[12] += w3.x * yv; acc[13] += w3.y * yv; acc[14] += w3.z * yv; acc[15] += w3.w * yv;
    }
    #pragma unroll
    for (int i = 0; i < 16; ++i) {
        int o = og * 16 + i;
        m_out[((size_t)b * CN + o) * HWN + yr * WN + x0 + px] = acc[i];
    }
}

// ---------------------------------------------------------------------------
extern "C" void kernel_launch(void* const* d_in, const int* in_sizes, int n_in,
                              void* d_out, int out_size, void* d_ws, size_t ws_size,
                              hipStream_t stream) {
    const float* x1    = (const float*)d_in[0];   // 2*64*192*192
    const float* w_off1 = (const float*)d_in[1];  // 256*9
    const float* w_off2 = (const float*)d_in[2];  // 72*256
    const float* b_off2 = (const float*)d_in[3];  // 72
    const float* w_def = (const float*)d_in[4];   // 64*9
    const float* w_out = (const float*)d_in[5];   // 64*64

    float* out = (float*)d_out;
    const size_t n_x = (size_t)BN * CN * HWN;     // 4718592
    float* out_x1 = out;                          // output 0: x1 copy (fused into k_offsets)
    float* out_m  = out + n_x;                    // output 1: m

    // Workspace layout (bytes)
    char* ws0 = (char*)d_ws;
    unsigned short* w2mf = (unsigned short*)ws0;            // 20480 bf16 = 40960 B
    float* w_outT = (float*)(ws0 + 40960);                  // 4096 f = 16384 B
    float* t_ws   = (float*)(ws0 + 57344);                  // 2*72*36864 f
    float* y_ws   = t_ws + (size_t)BN * JCN * HWN;          // 2*64*36864 f

    dim3 blk(256);

    k_prep<<<dim3(96), blk, 0, stream>>>(w_off2, w_out, w2mf, w_outT);
    k_offsets<<<dim3(WN / 64, HN, BN), blk, 0, stream>>>(x1, w_off1, w2mf, b_off2,
                                                         t_ws, out_x1);
    k_deform<<<dim3(WN / SN, HN / DROWS, BN * 8), blk, 0, stream>>>(x1, t_ws, w_def, y_ws);
    k_final<<<dim3(WN / 64, HN, BN), blk, 0, stream>>>(y_ws, w_outT, out_m);
}

// Round 9
// 193.021 us; speedup vs baseline: 1.0874x; 1.0472x over previous
//
#include <hip/hip_runtime.h>

// Problem constants (B=2, C=64, H=W=192, EXP=4, DG=4, K=3)
#define BN   2
#define CN   64
#define HN   192
#define WN   192
#define HWN  36864          // 192*192
#define OCN  256            // EXP*C
#define JCN  72             // DG*2*9
#define SN   32             // pixel strip for deform

// k_deform tile geometry
#define DROWS 8             // output rows per block
#define XH    17            // staged x rows
#define XW    42            // staged x cols
#define XRT   4             // row halo top
#define XCL   4             // col halo left

typedef __attribute__((ext_vector_type(8))) short bf16x8;
typedef __attribute__((ext_vector_type(4))) float f32x4;

__device__ __forceinline__ unsigned short f2bf(float f) {
    union { float f; unsigned u; } v; v.f = f;
    unsigned r = v.u + 0x7fffu + ((v.u >> 16) & 1u);
    return (unsigned short)(r >> 16);
}

// ---------------------------------------------------------------------------
// Prep:
//  job 1: w2mf = w2 (72x256) bf16, MFMA A-fragment order:
//         w2mf[((tm*8+s)*64 + l)*8 + j] = w2[tm*16+(l&15)][s*32+(l>>4)*8+j]
//  job 2: w_outT[c*64+o] = w_out[o*64+c]
//  job 3: w1p[o*8+kk] = w1[o*9+k(kk)], k skips center (kk<4?kk:kk+1);
//         o = 32s+8q+j so a (s,q)-quad's 8 rows are contiguous (64 floats).
// ---------------------------------------------------------------------------
__global__ __launch_bounds__(256) void k_prep(const float* __restrict__ w2,
                                              const float* __restrict__ w_out,
                                              const float* __restrict__ w1,
                                              unsigned short* __restrict__ w2mf,
                                              float* __restrict__ w_outT,
                                              float* __restrict__ w1p) {
    int idx = blockIdx.x * 256 + threadIdx.x;
    if (idx < 20480) {
        int j  = idx & 7;
        int l  = (idx >> 3) & 63;
        int ts = idx >> 9;             // tm*8+s, 0..39
        int tm = ts >> 3, s = ts & 7;
        int jrow = tm * 16 + (l & 15);
        int k    = s * 32 + (l >> 4) * 8 + j;
        float v = (jrow < JCN) ? w2[jrow * OCN + k] : 0.f;
        w2mf[idx] = f2bf(v);
    } else if (idx < 24576) {
        int r = idx - 20480;
        int c = r >> 6, o = r & 63;
        w_outT[r] = w_out[o * CN + c];
    } else if (idx < 26624) {
        int r = idx - 24576;           // 0..2047
        int o = r >> 3, kk = r & 7;
        int k = kk < 4 ? kk : kk + 1;
        w1p[r] = w1[o * 9 + k];
    }
}

// ---------------------------------------------------------------------------
// K1: offsets t + fused x1 copy.  Fully fused MFMA version: NO LDS, NO
// barriers. Wave owns a 16-px column slab; thread l computes xd[o][n] for
// exactly the o's its MFMA B-fragment lane needs (o = 32s + (l>>4)*8 + j),
// so B-frags materialize in registers. 8 chunks of K=32, tap ping-pong.
// ---------------------------------------------------------------------------
__global__ __launch_bounds__(256, 4) void k_offsets(const float* __restrict__ x,
                                                    const float* __restrict__ w1p,
                                                    const unsigned short* __restrict__ w2mf,
                                                    const float* __restrict__ b2,
                                                    float* __restrict__ t_out,
                                                    float* __restrict__ x_copy) {
    const int tid  = threadIdx.x;
    const int wv   = tid >> 6;
    const int lane = tid & 63;
    const int q    = lane >> 4;
    const int n    = lane & 15;
    const int n0   = blockIdx.x * 64 + wv * 16;
    const int y    = blockIdx.y;
    const int b    = blockIdx.z;
    const int xcol = n0 + n;
    const float* xb = x + (size_t)b * CN * HWN;

    auto load_chunk = [&](int s, float (*ld)[9]) {
        #pragma unroll
        for (int cc = 0; cc < 2; ++cc) {
            int c = 8 * s + 2 * q + cc;
            const float* xp = xb + (size_t)c * HWN;
            #pragma unroll
            for (int k = 0; k < 9; ++k) {
                int ky = k / 3, kx = k - 3 * ky;
                int yy = y - 1 + ky, xx = xcol - 1 + kx;
                float v = 0.f;
                if ((unsigned)yy < (unsigned)HN && (unsigned)xx < (unsigned)WN)
                    v = xp[yy * WN + xx];
                ld[cc][k] = v;
            }
        }
    };

    f32x4 acc[5];
    #pragma unroll
    for (int t = 0; t < 5; ++t) acc[t] = (f32x4){0.f, 0.f, 0.f, 0.f};

    const bf16x8* ap = (const bf16x8*)w2mf + lane;

    float lbuf[2][2][9];
    load_chunk(0, lbuf[0]);
    #pragma unroll
    for (int s = 0; s < 8; ++s) {
        if (s < 7) load_chunk(s + 1, lbuf[(s + 1) & 1]);
        float (*ld)[9] = lbuf[s & 1];

        float dd[2][8];
        #pragma unroll
        for (int cc = 0; cc < 2; ++cc) {
            int c = 8 * s + 2 * q + cc;
            float ctr = ld[cc][4];
            x_copy[((size_t)b * CN + c) * HWN + y * WN + xcol] = ctr;
            #pragma unroll
            for (int kk = 0; kk < 8; ++kk) {
                int k = kk < 4 ? kk : kk + 1;
                dd[cc][kk] = ld[cc][k] - ctr;
            }
        }

        // xd for this thread's 8 o's (j=0..7) -> B-fragment
        bf16x8 bfr;
        const float4* wp = (const float4*)(w1p + (size_t)(s * 32 + q * 8) * 8);
        #pragma unroll
        for (int j = 0; j < 8; ++j) {
            float4 wa = wp[2 * j];
            float4 wb = wp[2 * j + 1];
            const float* d = dd[j >> 2];
            float a = wa.x * d[0] + wa.y * d[1] + wa.z * d[2] + wa.w * d[3]
                    + wb.x * d[4] + wb.y * d[5] + wb.z * d[6] + wb.w * d[7];
            bfr[j] = (short)f2bf(a);
        }

        #pragma unroll
        for (int tm = 0; tm < 5; ++tm) {
            bf16x8 af = ap[(tm * 8 + s) * 64];
            acc[tm] = __builtin_amdgcn_mfma_f32_16x16x32_bf16(af, bfr, acc[tm], 0, 0, 0);
        }
    }

    // Epilogue (D layout: col=lane&15, row=q*4+reg)
    float* tb = t_out + (size_t)b * JCN * HWN + y * WN + n0 + n;
    #pragma unroll
    for (int tm = 0; tm < 5; ++tm) {
        #pragma unroll
        for (int r = 0; r < 4; ++r) {
            int j = tm * 16 + q * 4 + r;
            if (j < JCN)
                tb[(size_t)j * HWN] = acc[tm][r] + b2[j];
        }
    }
}

// ---------------------------------------------------------------------------
// K2: depthwise deformable conv (round-8 state: (256,4), reg offsets).
// ---------------------------------------------------------------------------
__device__ __forceinline__ float dsample(const float* __restrict__ p, int yi, int xi) {
    if ((unsigned)yi < (unsigned)HN && (unsigned)xi < (unsigned)WN)
        return p[yi * WN + xi];
    return 0.f;
}

__global__ __launch_bounds__(256, 4) void k_deform(const float* __restrict__ x,
                                                   const float* __restrict__ t_in,
                                                   const float* __restrict__ wdef,
                                                   float* __restrict__ y_out) {
    __shared__ float xs[8 * XH * XW];                 // 22848 B
    __shared__ float wks[9 * 8];                      // [k][cc]
    __shared__ float wsums[8];
    const int x0   = blockIdx.x * SN;
    const int yr0  = blockIdx.y * DROWS;
    const int zz   = blockIdx.z;
    const int b    = zz >> 3;
    const int chunk = zz & 7;                         // 8-channel chunk
    const int g    = chunk >> 1;                      // deform group
    const int tid  = threadIdx.x;
    const int r    = tid >> 5;                        // output row within tile
    const int px   = tid & 31;
    const int row_lo = yr0 - XRT;
    const int col_lo = x0 - XCL;
    const float* xb = x + (size_t)b * CN * HWN;

    // prefetch this thread's 18 offsets into registers (coalesced)
    float dyr[9], dxr[9];
    {
        const float* tbp = t_in + ((size_t)b * JCN + g * 18) * HWN
                         + (yr0 + r) * WN + x0 + px;
        #pragma unroll
        for (int k = 0; k < 9; ++k) {
            dyr[k] = tbp[(size_t)(2 * k) * HWN];
            dxr[k] = tbp[(size_t)(2 * k + 1) * HWN];
        }
    }

    // stage x window (zero-filled outside image)
    for (int idx = tid; idx < 8 * XH * XW; idx += 256) {
        int cc  = idx / (XH * XW);
        int rem = idx - cc * (XH * XW);
        int rr  = rem / XW;
        int col = rem - rr * XW;
        int yy  = row_lo + rr;
        int xx  = col_lo + col;
        float v = 0.f;
        if ((unsigned)yy < (unsigned)HN && (unsigned)xx < (unsigned)WN)
            v = xb[(size_t)(chunk * 8 + cc) * HWN + yy * WN + xx];
        xs[idx] = v;
    }
    // stage weights
    if (tid < 72) {
        int k = tid >> 3, cc = tid & 7;
        wks[tid] = wdef[(chunk * 8 + cc) * 9 + k];
    } else if (tid < 80) {
        int cc = tid - 72;
        float s = 0.f;
        #pragma unroll
        for (int k = 0; k < 9; ++k) s += wdef[(chunk * 8 + cc) * 9 + k];
        wsums[cc] = s;
    }
    __syncthreads();

    float acc[8];
    #pragma unroll
    for (int c = 0; c < 8; ++c)
        acc[c] = -xs[c * (XH * XW) + (XRT + r) * XW + XCL + px] * wsums[c];

    const float ry_basef = (float)(yr0 + r - 1);
    const float rx_basef = (float)(x0 + px - 1);

    #pragma unroll
    for (int k = 0; k < 9; ++k) {
        const int ky = k / 3, kx = k - 3 * ky;
        float py  = ry_basef + (float)ky + dyr[k];
        float pxf = rx_basef + (float)kx + dxr[k];
        float y0f = floorf(py), x0f = floorf(pxf);
        float wy = py - y0f, wx = pxf - x0f;
        int yi = (int)y0f, xi = (int)x0f;
        int ry = yi - row_lo, rx = xi - col_lo;
        float omwy = 1.f - wy, omwx = 1.f - wx;
        float w00 = omwy * omwx;
        float w01 = omwy * wx;
        float w10 = wy * omwx;
        float w11 = wy * wx;
        float4 wka = *(const float4*)&wks[k * 8];
        float4 wkb = *(const float4*)&wks[k * 8 + 4];
        float wkv[8] = {wka.x, wka.y, wka.z, wka.w, wkb.x, wkb.y, wkb.z, wkb.w};
        if ((unsigned)ry < (XH - 1) && (unsigned)rx < (XW - 1)) {
            const float* p0 = xs + ry * XW + rx;
            #pragma unroll
            for (int c = 0; c < 8; ++c) {
                const float* p = p0 + c * (XH * XW);
                float bil = p[0] * w00 + p[1] * w01 + p[XW] * w10 + p[XW + 1] * w11;
                acc[c] += wkv[c] * bil;
            }
        } else {
            #pragma unroll
            for (int c = 0; c < 8; ++c) {
                const float* xp = xb + (size_t)(chunk * 8 + c) * HWN;
                float v00 = dsample(xp, yi,     xi);
                float v01 = dsample(xp, yi,     xi + 1);
                float v10 = dsample(xp, yi + 1, xi);
                float v11 = dsample(xp, yi + 1, xi + 1);
                float bil = v00 * w00 + v01 * w01 + v10 * w10 + v11 * w11;
                acc[c] += wkv[c] * bil;
            }
        }
    }

    float* yo = y_out + ((size_t)b * CN + chunk * 8) * HWN + (yr0 + r) * WN + x0 + px;
    #pragma unroll
    for (int c = 0; c < 8; ++c)
        yo[(size_t)c * HWN] = acc[c];
}

// ---------------------------------------------------------------------------
// K3: m = w_out . y  (64-px tile, pre-transposed weights, 16 o/thread)
// ---------------------------------------------------------------------------
__global__ __launch_bounds__(256, 4) void k_final(const float* __restrict__ y_in,
                                                  const float* __restrict__ w_outT,
                                                  float* __restrict__ m_out) {
    __shared__ float lds_y[CN * 64];     // 16 KB
    __shared__ float ldsw[CN * CN];      // 16 KB  [c][o]
    const int x0  = blockIdx.x * 64;
    const int yr  = blockIdx.y;
    const int b   = blockIdx.z;
    const int tid = threadIdx.x;

    for (int idx = tid; idx < CN * CN; idx += 256) ldsw[idx] = w_outT[idx];
    for (int idx = tid; idx < CN * 64; idx += 256) {
        int c  = idx >> 6;
        int px = idx & 63;
        lds_y[idx] = y_in[((size_t)b * CN + c) * HWN + yr * WN + x0 + px];
    }
    __syncthreads();

    const int px = tid & 63;
    const int og = tid >> 6;                      // 16 o's per thread
    float acc[16];
    #pragma unroll
    for (int i = 0; i < 16; ++i) acc[i] = 0.f;
    #pragma unroll 4
    for (int c = 0; c < CN; ++c) {
        float yv = lds_y[c * 64 + px];
        const float4* wr = (const float4*)(ldsw + c * CN + og * 16);
        float4 w0 = wr[0], w1 = wr[1], w2 = wr[2], w3 = wr[3];
        acc[0]  += w0.x * yv; acc[1]  += w0.y * yv; acc[2]  += w0.z * yv; acc[3]  += w0.w * yv;
        acc[4]  += w1.x * yv; acc[5]  += w1.y * yv; acc[6]  += w1.z * yv; acc[7]  += w1.w * yv;
        acc[8]  += w2.x * yv; acc[9]  += w2.y * yv; acc[10] += w2.z * yv; acc[11] += w2.w * yv;
        acc[12] += w3.x * yv; acc[13] += w3.y * yv; acc[14] += w3.z * yv; acc[15] += w3.w * yv;
    }
    #pragma unroll
    for (int i = 0; i < 16; ++i) {
        int o = og * 16 + i;
        m_out[((size_t)b * CN + o) * HWN + yr * WN + x0 + px] = acc[i];
    }
}

// ---------------------------------------------------------------------------
extern "C" void kernel_launch(void* const* d_in, const int* in_sizes, int n_in,
                              void* d_out, int out_size, void* d_ws, size_t ws_size,
                              hipStream_t stream) {
    const float* x1    = (const float*)d_in[0];   // 2*64*192*192
    const float* w_off1 = (const float*)d_in[1];  // 256*9
    const float* w_off2 = (const float*)d_in[2];  // 72*256
    const float* b_off2 = (const float*)d_in[3];  // 72
    const float* w_def = (const float*)d_in[4];   // 64*9
    const float* w_out = (const float*)d_in[5];   // 64*64

    float* out = (float*)d_out;
    const size_t n_x = (size_t)BN * CN * HWN;     // 4718592
    float* out_x1 = out;                          // output 0: x1 copy (fused into k_offsets)
    float* out_m  = out + n_x;                    // output 1: m

    // Workspace layout (bytes)
    char* ws0 = (char*)d_ws;
    unsigned short* w2mf = (unsigned short*)ws0;            // 20480 bf16 = 40960 B
    float* w_outT = (float*)(ws0 + 40960);                  // 4096 f = 16384 B
    float* w1p    = (float*)(ws0 + 57344);                  // 2048 f = 8192 B
    float* t_ws   = (float*)(ws0 + 65536);                  // 2*72*36864 f
    float* y_ws   = t_ws + (size_t)BN * JCN * HWN;          // 2*64*36864 f

    dim3 blk(256);

    k_prep<<<dim3(104), blk, 0, stream>>>(w_off2, w_out, w_off1, w2mf, w_outT, w1p);
    k_offsets<<<dim3(WN / 64, HN, BN), blk, 0, stream>>>(x1, w1p, w2mf, b_off2,
                                                         t_ws, out_x1);
    k_deform<<<dim3(WN / SN, HN / DROWS, BN * 8), blk, 0, stream>>>(x1, t_ws, w_def, y_ws);
    k_final<<<dim3(WN / 64, HN, BN), blk, 0, stream>>>(y_ws, w_outT, out_m);
}